// Round 9
// baseline (332.185 us; speedup 1.0000x reference)
//
#include <hip/hip_runtime.h>

#define N1c 25000
#define N2c 5000
#define Dc 256
#define DOUTc 128
#define EPSc 1e-5f
#define NEGc 0.01f

typedef __attribute__((ext_vector_type(8))) short short8;
typedef __attribute__((ext_vector_type(4))) float f32x4;

__device__ __forceinline__ ushort f2bf(float f) {
    unsigned u = __float_as_uint(f);
    u += 0x7fffu + ((u >> 16) & 1u);          // round-to-nearest-even
    return (ushort)(u >> 16);
}
__device__ __forceinline__ float bf2f(ushort u) {
    return __uint_as_float(((unsigned)u) << 16);
}
__device__ __forceinline__ unsigned pack2(float lo, float hi) {
    return ((unsigned)f2bf(lo)) | (((unsigned)f2bf(hi)) << 16);
}

// ---------------- prep_all: Bt1/Bt2 transpose+bf16, mask1, count0/1 ---------
__global__ __launch_bounds__(256) void prep_all(
    const int* __restrict__ dst0, const int* __restrict__ val0,
    const int* __restrict__ dst1, const int* __restrict__ val1,
    const int* __restrict__ ts, const int* __restrict__ time_p, const int* __restrict__ itv_p,
    const float* __restrict__ W1l, const float* __restrict__ W1r,
    const float* __restrict__ W2l, const float* __restrict__ W2r,
    int E0, int E1,
    ushort* __restrict__ Bt1, ushort* __restrict__ Bt2,
    int* __restrict__ count0, int* __restrict__ count1,
    float* __restrict__ mask_out) {
    const int flat = blockIdx.x * blockDim.x + threadIdx.x;
    const int NT = gridDim.x * blockDim.x;
    const int t0 = *time_p, iv = *itv_p;

    for (int i = flat; i < 256 * 512; i += NT) {   // Bt1 [n][512]
        int n = i >> 9, k = i & 511;
        float v = (k < 256) ? W1l[(size_t)k * 256 + n] : W1r[(size_t)(k - 256) * 256 + n];
        Bt1[i] = f2bf(v);
    }
    for (int i = flat; i < 128 * 512; i += NT) {   // Bt2 [n][512]
        int n = i >> 9, k = i & 511;
        float v = (k < 256) ? W2l[(size_t)k * 128 + n] : W2r[(size_t)(k - 256) * 128 + n];
        Bt2[i] = f2bf(v);
    }
    for (int e = flat; e < E1; e += NT) {          // mask1 -> out tail
        int t = ts[val1[e]];
        mask_out[e] = (t >= t0 && t < t0 + iv) ? 1.0f : 0.0f;
    }
    for (int e = flat; e < E0; e += NT) {
        int t = ts[val0[e]];
        if (t >= t0 && t < t0 + iv) atomicAdd(&count0[dst0[e]], 1);
    }
    for (int e = flat; e < E1; e += NT) {
        int t = ts[val1[e]];
        if (t >= t0 && t < t0 + iv) atomicAdd(&count1[dst1[e]], 1);
    }
}

// ---------------- scan: shuffle-based, 2 barriers total ---------------------
// Writes EXCLUSIVE offsets (offsets[i] = sum count[0..i)), length n.
template <int CH>
__device__ __forceinline__ void scan_block(const int* __restrict__ count,
                                           int* __restrict__ offsets, int n) {
    __shared__ int wsum[16];
    int t = threadIdx.x;
    int lane = t & 63, w = t >> 6;                 // 16 waves of 64
    int v[CH];
    int base = t * CH;
    int run = 0;
#pragma unroll
    for (int i = 0; i < CH; ++i) {
        int c = (base + i < n) ? count[base + i] : 0;
        v[i] = run;                                // exclusive within thread
        run += c;
    }
    int incl = run;
#pragma unroll
    for (int off = 1; off < 64; off <<= 1) {
        int s = __shfl_up(incl, off, 64);
        if (lane >= off) incl += s;
    }
    if (lane == 63) wsum[w] = incl;
    __syncthreads();
    if (t == 0) {
        int s = 0;
#pragma unroll
        for (int i = 0; i < 16; ++i) { int c = wsum[i]; wsum[i] = s; s += c; }
    }
    __syncthreads();
    int pre = wsum[w] + (incl - run);
#pragma unroll
    for (int i = 0; i < CH; ++i) {
        int idx = base + i;
        if (idx < n) offsets[idx] = pre + v[i];
    }
}

__global__ __launch_bounds__(1024) void scan_both(
    const int* __restrict__ count0, int* __restrict__ offsets0,
    const int* __restrict__ count1, int* __restrict__ offsets1) {
    if (blockIdx.x == 0) scan_block<25>(count0, offsets0, N1c);
    else                 scan_block<5>(count1, offsets1, N2c);
}

// ---------------- fill_both: offsets-as-cursor (exclusive -> inclusive) -----
__global__ __launch_bounds__(256) void fill_both(
    const int* __restrict__ src0, const int* __restrict__ dst0, const int* __restrict__ val0,
    const int* __restrict__ src1, const int* __restrict__ dst1, const int* __restrict__ val1,
    const int* __restrict__ ts, const int* __restrict__ time_p, const int* __restrict__ itv_p,
    int E0, int E1,
    int* __restrict__ offsets0, int* __restrict__ offsets1,
    int* __restrict__ eidx0, int* __restrict__ eidx1) {
    int e = blockIdx.x * blockDim.x + threadIdx.x;
    int t0 = *time_p, iv = *itv_p;
    if (e < E0) {
        int t = ts[val0[e]];
        if (t >= t0 && t < t0 + iv) {
            int pos = atomicAdd(&offsets0[dst0[e]], 1);
            eidx0[pos] = src0[e];
        }
    } else if (e < E0 + E1) {
        int e1 = e - E0;
        int t = ts[val1[e1]];
        if (t >= t0 && t < t0 + iv) {
            int pos = atomicAdd(&offsets1[dst1[e1]], 1);
            eidx1[pos] = src1[e1];
        }
    }
}

// ======== gemm0_fused: gather(x)+mean -> [agg|x] @ Bt1^T + BN + leaky -> h ==
// BM=64, BN=256 (full), 256 thr (4 waves). Wave w owns rows w*16..+15.
// Prologue gathers agg rows into LDS Af (bf16); x-half staged per K-chunk
// with in-register fp32->bf16. Offsets are INCLUSIVE (post-fill).
__global__ __launch_bounds__(256) void gemm0_fused(
    const float* __restrict__ x,
    const int* __restrict__ off, const int* __restrict__ eidx,
    const ushort* __restrict__ Bt,
    const float* __restrict__ bias,
    const float* __restrict__ g, const float* __restrict__ bt,
    const float* __restrict__ rm, const float* __restrict__ rv,
    ushort* __restrict__ h, int M) {
    __shared__ ushort Af[64][264];    // gathered rows, K 0..255 (+8 pad)
    __shared__ ushort As2[64][40];    // x-half chunk
    __shared__ ushort Bs[256][40];
    int tid = threadIdx.x;
    int wave = tid >> 6, lane = tid & 63;
    int quad = lane >> 4, l16 = lane & 15;
    int m0 = blockIdx.x * 64;

    for (int i = wave; i < 64; i += 4) {           // gather prologue
        int row = m0 + i;
        float4 acc = make_float4(0.f, 0.f, 0.f, 0.f);
        int deg = 0;
        if (row < M) {
            int s1 = off[row], s0 = row ? off[row - 1] : 0;
            deg = s1 - s0;
            for (int j = s0; j < s1; ++j) {
                int s = eidx[j];
                float4 v = *(const float4*)(x + (size_t)s * Dc + lane * 4);
                acc.x += v.x; acc.y += v.y; acc.z += v.z; acc.w += v.w;
            }
        }
        float inv = 1.0f / fmaxf((float)deg, 1.0f);
        ushort4 o;
        o.x = f2bf(acc.x * inv); o.y = f2bf(acc.y * inv);
        o.z = f2bf(acc.z * inv); o.w = f2bf(acc.w * inv);
        *(ushort4*)&Af[i][lane * 4] = o;
    }
    __syncthreads();

    f32x4 acc[16] = {};
    int bn = tid;                 // B stage: one n-row per thread (256)
    int ar2 = tid >> 2;           // A2 stage: row 0..63
    int ak2 = (tid & 3) * 8;      // 8 bf16 per thread
    for (int k0 = 0; k0 < 512; k0 += 32) {
        const ushort* Bg = Bt + (size_t)bn * 512 + k0;
        uint4 b0 = *(const uint4*)(Bg + 0);
        uint4 b1 = *(const uint4*)(Bg + 8);
        uint4 b2 = *(const uint4*)(Bg + 16);
        uint4 b3 = *(const uint4*)(Bg + 24);
        uint4 a2 = make_uint4(0, 0, 0, 0);
        if (k0 >= 256 && m0 + ar2 < M) {
            const float* Ap = x + (size_t)(m0 + ar2) * Dc + (k0 - 256) + ak2;
            float4 f0 = *(const float4*)(Ap + 0);
            float4 f1 = *(const float4*)(Ap + 4);
            a2 = make_uint4(pack2(f0.x, f0.y), pack2(f0.z, f0.w),
                            pack2(f1.x, f1.y), pack2(f1.z, f1.w));
        }
        __syncthreads();          // prior chunk's LDS reads done
        *(uint4*)&Bs[bn][0]  = b0;
        *(uint4*)&Bs[bn][8]  = b1;
        *(uint4*)&Bs[bn][16] = b2;
        *(uint4*)&Bs[bn][24] = b3;
        if (k0 >= 256) *(uint4*)&As2[ar2][ak2] = a2;
        __syncthreads();
        short8 af = (k0 < 256)
            ? *(const short8*)&Af[wave * 16 + l16][k0 + quad * 8]
            : *(const short8*)&As2[wave * 16 + l16][quad * 8];
#pragma unroll
        for (int j = 0; j < 16; ++j) {
            short8 bf = *(const short8*)&Bs[j * 16 + l16][quad * 8];
            acc[j] = __builtin_amdgcn_mfma_f32_16x16x32_bf16(af, bf, acc[j], 0, 0, 0);
        }
    }
    // epilogue: C/D layout col=l16, row=quad*4+r (within wave's 16-row group)
#pragma unroll
    for (int j = 0; j < 16; ++j) {
        int gn = j * 16 + l16;
        float s = g[gn] * rsqrtf(rv[gn] + EPSc);
        float sh = (bias[gn] - rm[gn]) * s + bt[gn];
        int gmb = m0 + wave * 16 + quad * 4;
#pragma unroll
        for (int r = 0; r < 4; ++r) {
            int gm = gmb + r;
            if (gm >= M) continue;
            float v = acc[j][r] * s + sh;
            v = v >= 0.f ? v : NEGc * v;
            h[(size_t)gm * Dc + gn] = f2bf(v);
        }
    }
}

// ======== gemm1_fused: gather(h)+mean -> [agg|h] @ Bt2^T + bias -> out ======
// BM=32, BN=128, 128 thr (2 waves).
__global__ __launch_bounds__(128) void gemm1_fused(
    const ushort* __restrict__ hsrc,
    const int* __restrict__ off, const int* __restrict__ eidx,
    const ushort* __restrict__ Bt,
    const float* __restrict__ bias,
    float* __restrict__ out, int M) {
    __shared__ ushort Af[32][264];
    __shared__ ushort As2[32][40];
    __shared__ ushort Bs[128][40];
    int tid = threadIdx.x;
    int wave = tid >> 6, lane = tid & 63;
    int quad = lane >> 4, l16 = lane & 15;
    int m0 = blockIdx.x * 32;

    for (int i = wave; i < 32; i += 2) {           // gather prologue (bf16 h)
        int row = m0 + i;
        float4 acc = make_float4(0.f, 0.f, 0.f, 0.f);
        int deg = 0;
        if (row < M) {
            int s1 = off[row], s0 = row ? off[row - 1] : 0;
            deg = s1 - s0;
            for (int j = s0; j < s1; ++j) {
                int s = eidx[j];
                ushort4 v = *(const ushort4*)(hsrc + (size_t)s * Dc + lane * 4);
                acc.x += bf2f(v.x); acc.y += bf2f(v.y);
                acc.z += bf2f(v.z); acc.w += bf2f(v.w);
            }
        }
        float inv = 1.0f / fmaxf((float)deg, 1.0f);
        ushort4 o;
        o.x = f2bf(acc.x * inv); o.y = f2bf(acc.y * inv);
        o.z = f2bf(acc.z * inv); o.w = f2bf(acc.w * inv);
        *(ushort4*)&Af[i][lane * 4] = o;
    }
    __syncthreads();

    f32x4 acc[8] = {};
    int bn = tid;                 // 0..127: one Bt2 row each
    int ar2 = tid >> 2;           // 0..31
    int ak2 = (tid & 3) * 8;
    for (int k0 = 0; k0 < 512; k0 += 32) {
        const ushort* Bg = Bt + (size_t)bn * 512 + k0;
        uint4 b0 = *(const uint4*)(Bg + 0);
        uint4 b1 = *(const uint4*)(Bg + 8);
        uint4 b2 = *(const uint4*)(Bg + 16);
        uint4 b3 = *(const uint4*)(Bg + 24);
        uint4 a2 = make_uint4(0, 0, 0, 0);
        if (k0 >= 256 && m0 + ar2 < M)
            a2 = *(const uint4*)(hsrc + (size_t)(m0 + ar2) * Dc + (k0 - 256) + ak2);
        __syncthreads();
        *(uint4*)&Bs[bn][0]  = b0;
        *(uint4*)&Bs[bn][8]  = b1;
        *(uint4*)&Bs[bn][16] = b2;
        *(uint4*)&Bs[bn][24] = b3;
        if (k0 >= 256) *(uint4*)&As2[ar2][ak2] = a2;
        __syncthreads();
        short8 af = (k0 < 256)
            ? *(const short8*)&Af[wave * 16 + l16][k0 + quad * 8]
            : *(const short8*)&As2[wave * 16 + l16][quad * 8];
#pragma unroll
        for (int j = 0; j < 8; ++j) {
            short8 bf = *(const short8*)&Bs[j * 16 + l16][quad * 8];
            acc[j] = __builtin_amdgcn_mfma_f32_16x16x32_bf16(af, bf, acc[j], 0, 0, 0);
        }
    }
#pragma unroll
    for (int j = 0; j < 8; ++j) {
        int gn = j * 16 + l16;
        float sh = bias[gn];
        int gmb = m0 + wave * 16 + quad * 4;
#pragma unroll
        for (int r = 0; r < 4; ++r) {
            int gm = gmb + r;
            if (gm >= M) continue;
            out[(size_t)gm * DOUTc + gn] = acc[j][r] + sh;
        }
    }
}

extern "C" void kernel_launch(void* const* d_in, const int* in_sizes, int n_in,
                              void* d_out, int out_size, void* d_ws, size_t ws_size,
                              hipStream_t stream) {
    const float* x    = (const float*)d_in[0];
    const int* src0   = (const int*)d_in[1];
    const int* dst0   = (const int*)d_in[2];
    const int* val0   = (const int*)d_in[3];
    const int* src1   = (const int*)d_in[4];
    const int* dst1   = (const int*)d_in[5];
    const int* val1   = (const int*)d_in[6];
    const int* ts     = (const int*)d_in[7];
    const int* time_p = (const int*)d_in[8];
    const int* itv_p  = (const int*)d_in[9];
    const float* W1l  = (const float*)d_in[10];
    const float* W1r  = (const float*)d_in[11];
    const float* b1   = (const float*)d_in[12];
    const float* g1   = (const float*)d_in[13];
    const float* bt1  = (const float*)d_in[14];
    const float* rm1  = (const float*)d_in[15];
    const float* rv1  = (const float*)d_in[16];
    const float* W2l  = (const float*)d_in[17];
    const float* W2r  = (const float*)d_in[18];
    const float* b2   = (const float*)d_in[19];
    int E0 = in_sizes[1];
    int E1 = in_sizes[4];
    float* out = (float*)d_out;

    // ---- workspace layout ----
    ushort* h    = (ushort*)d_ws;                  // [N1][256]
    ushort* Bt1  = h + (size_t)N1c * Dc;           // [256][512]
    ushort* Bt2  = Bt1 + 256 * 512;                // [128][512]
    int* ip      = (int*)(Bt2 + 128 * 512);
    int* count0   = ip;            ip += N1c;      // -- zeroed (memset)
    int* count1   = ip;            ip += N2c;      // -- zeroed (memset)
    int* offsets0 = ip;            ip += N1c;
    int* offsets1 = ip;            ip += N2c;
    int* eidx0    = ip;            ip += E0;
    int* eidx1    = ip;            ip += E1;
    float* mask_tail = out + (size_t)N2c * DOUTc;

    hipMemsetAsync(count0, 0, (size_t)(N1c + N2c) * sizeof(int), stream);

    prep_all<<<1024, 256, 0, stream>>>(
        dst0, val0, dst1, val1, ts, time_p, itv_p,
        W1l, W1r, W2l, W2r, E0, E1, Bt1, Bt2, count0, count1, mask_tail);
    scan_both<<<2, 1024, 0, stream>>>(count0, offsets0, count1, offsets1);
    fill_both<<<(E0 + E1 + 255) / 256, 256, 0, stream>>>(
        src0, dst0, val0, src1, dst1, val1, ts, time_p, itv_p,
        E0, E1, offsets0, offsets1, eidx0, eidx1);
    gemm0_fused<<<(N1c + 63) / 64, 256, 0, stream>>>(
        x, offsets0, eidx0, Bt1, b1, g1, bt1, rm1, rv1, h, N1c);
    gemm1_fused<<<(N2c + 31) / 32, 128, 0, stream>>>(
        h, offsets1, eidx1, Bt2, b2, out, N2c);
}

// Round 10
// 278.769 us; speedup vs baseline: 1.1916x; 1.1916x over previous
//
#include <hip/hip_runtime.h>

#define N1c 25000
#define N2c 5000
#define Dc 256
#define DOUTc 128
#define EPSc 1e-5f
#define NEGc 0.01f

typedef __attribute__((ext_vector_type(8))) short short8;
typedef __attribute__((ext_vector_type(4))) float f32x4;

__device__ __forceinline__ ushort f2bf(float f) {
    unsigned u = __float_as_uint(f);
    u += 0x7fffu + ((u >> 16) & 1u);          // round-to-nearest-even
    return (ushort)(u >> 16);
}
__device__ __forceinline__ float bf2f(ushort u) {
    return __uint_as_float(((unsigned)u) << 16);
}
__device__ __forceinline__ unsigned pack2(float lo, float hi) {
    return ((unsigned)f2bf(lo)) | (((unsigned)f2bf(hi)) << 16);
}

// ---------------- prep_all: Bt1/Bt2 transpose+bf16, count0/1 ----------------
// counts pre-zeroed by hipMemsetAsync. (mask1 moved to fill_both.)
__global__ __launch_bounds__(256) void prep_all(
    const int* __restrict__ dst0, const int* __restrict__ val0,
    const int* __restrict__ dst1, const int* __restrict__ val1,
    const int* __restrict__ ts, const int* __restrict__ time_p, const int* __restrict__ itv_p,
    const float* __restrict__ W1l, const float* __restrict__ W1r,
    const float* __restrict__ W2l, const float* __restrict__ W2r,
    int E0, int E1,
    ushort* __restrict__ Bt1, ushort* __restrict__ Bt2,
    int* __restrict__ count0, int* __restrict__ count1) {
    const int flat = blockIdx.x * blockDim.x + threadIdx.x;
    const int NT = gridDim.x * blockDim.x;
    const int t0 = *time_p, iv = *itv_p;

    for (int i = flat; i < 256 * 512; i += NT) {   // Bt1 [n][512]
        int n = i >> 9, k = i & 511;
        float v = (k < 256) ? W1l[(size_t)k * 256 + n] : W1r[(size_t)(k - 256) * 256 + n];
        Bt1[i] = f2bf(v);
    }
    for (int i = flat; i < 128 * 512; i += NT) {   // Bt2 [n][512]
        int n = i >> 9, k = i & 511;
        float v = (k < 256) ? W2l[(size_t)k * 128 + n] : W2r[(size_t)(k - 256) * 128 + n];
        Bt2[i] = f2bf(v);
    }
    for (int e = flat; e < E0; e += NT) {
        int t = ts[val0[e]];
        if (t >= t0 && t < t0 + iv) atomicAdd(&count0[dst0[e]], 1);
    }
    for (int e = flat; e < E1; e += NT) {
        int t = ts[val1[e]];
        if (t >= t0 && t < t0 + iv) atomicAdd(&count1[dst1[e]], 1);
    }
}

// ---------------- scan: shuffle-based, 2 barriers total ---------------------
// Writes EXCLUSIVE offsets (offsets[i] = sum count[0..i)), length n.
template <int CH>
__device__ __forceinline__ void scan_block(const int* __restrict__ count,
                                           int* __restrict__ offsets, int n) {
    __shared__ int wsum[16];
    int t = threadIdx.x;
    int lane = t & 63, w = t >> 6;                 // 16 waves of 64
    int v[CH];
    int base = t * CH;
    int run = 0;
#pragma unroll
    for (int i = 0; i < CH; ++i) {
        int c = (base + i < n) ? count[base + i] : 0;
        v[i] = run;                                // exclusive within thread
        run += c;
    }
    int incl = run;
#pragma unroll
    for (int off = 1; off < 64; off <<= 1) {
        int s = __shfl_up(incl, off, 64);
        if (lane >= off) incl += s;
    }
    if (lane == 63) wsum[w] = incl;
    __syncthreads();
    if (t == 0) {
        int s = 0;
#pragma unroll
        for (int i = 0; i < 16; ++i) { int c = wsum[i]; wsum[i] = s; s += c; }
    }
    __syncthreads();
    int pre = wsum[w] + (incl - run);
#pragma unroll
    for (int i = 0; i < CH; ++i) {
        int idx = base + i;
        if (idx < n) offsets[idx] = pre + v[i];
    }
}

__global__ __launch_bounds__(1024) void scan_both(
    const int* __restrict__ count0, int* __restrict__ offsets0,
    const int* __restrict__ count1, int* __restrict__ offsets1) {
    if (blockIdx.x == 0) scan_block<25>(count0, offsets0, N1c);
    else                 scan_block<5>(count1, offsets1, N2c);
}

// ------- fill_both + mask1: offsets-as-cursor (exclusive -> inclusive) ------
__global__ __launch_bounds__(256) void fill_both(
    const int* __restrict__ src0, const int* __restrict__ dst0, const int* __restrict__ val0,
    const int* __restrict__ src1, const int* __restrict__ dst1, const int* __restrict__ val1,
    const int* __restrict__ ts, const int* __restrict__ time_p, const int* __restrict__ itv_p,
    int E0, int E1,
    int* __restrict__ offsets0, int* __restrict__ offsets1,
    int* __restrict__ eidx0, int* __restrict__ eidx1,
    float* __restrict__ mask_out) {
    int e = blockIdx.x * blockDim.x + threadIdx.x;
    int t0 = *time_p, iv = *itv_p;
    if (e < E0) {
        int t = ts[val0[e]];
        if (t >= t0 && t < t0 + iv) {
            int pos = atomicAdd(&offsets0[dst0[e]], 1);
            eidx0[pos] = src0[e];
        }
    } else if (e < E0 + E1) {
        int e1 = e - E0;
        int t = ts[val1[e1]];
        bool m = (t >= t0 && t < t0 + iv);
        mask_out[e1] = m ? 1.0f : 0.0f;
        if (m) {
            int pos = atomicAdd(&offsets1[dst1[e1]], 1);
            eidx1[pos] = src1[e1];
        }
    }
}

// ---------------- gather + mean (fp32 x -> bf16 agg0), inclusive offsets ----
__global__ void gather_f32(const float* __restrict__ X,
                           const int* __restrict__ off,
                           const int* __restrict__ eidx,
                           ushort* __restrict__ agg, int n) {
    int wave = (blockIdx.x * blockDim.x + threadIdx.x) >> 6;
    int lane = threadIdx.x & 63;
    if (wave >= n) return;
    int s1 = off[wave];
    int s0 = wave ? off[wave - 1] : 0;
    float4 acc = make_float4(0.f, 0.f, 0.f, 0.f);
    for (int j = s0; j < s1; ++j) {
        int s = eidx[j];
        float4 v = *(const float4*)(X + (size_t)s * Dc + lane * 4);
        acc.x += v.x; acc.y += v.y; acc.z += v.z; acc.w += v.w;
    }
    float inv = 1.0f / fmaxf((float)(s1 - s0), 1.0f);
    ushort4 o;
    o.x = f2bf(acc.x * inv); o.y = f2bf(acc.y * inv);
    o.z = f2bf(acc.z * inv); o.w = f2bf(acc.w * inv);
    *(ushort4*)(agg + (size_t)wave * Dc + lane * 4) = o;
}

// ---------------- gather + mean (bf16 h -> bf16 agg1), inclusive offsets ----
__global__ void gather_bf16(const ushort* __restrict__ H,
                            const int* __restrict__ off,
                            const int* __restrict__ eidx,
                            ushort* __restrict__ agg, int n) {
    int wave = (blockIdx.x * blockDim.x + threadIdx.x) >> 6;
    int lane = threadIdx.x & 63;
    if (wave >= n) return;
    int s1 = off[wave];
    int s0 = wave ? off[wave - 1] : 0;
    float4 acc = make_float4(0.f, 0.f, 0.f, 0.f);
    for (int j = s0; j < s1; ++j) {
        int s = eidx[j];
        ushort4 v = *(const ushort4*)(H + (size_t)s * Dc + lane * 4);
        acc.x += bf2f(v.x); acc.y += bf2f(v.y);
        acc.z += bf2f(v.z); acc.w += bf2f(v.w);
    }
    float inv = 1.0f / fmaxf((float)(s1 - s0), 1.0f);
    ushort4 o;
    o.x = f2bf(acc.x * inv); o.y = f2bf(acc.y * inv);
    o.z = f2bf(acc.z * inv); o.w = f2bf(acc.w * inv);
    *(ushort4*)(agg + (size_t)wave * Dc + lane * 4) = o;
}

// ---------------- bf16 MFMA GEMM: C = [Alo|A2] @ Bt^T + bias [,BN+leaky] ----
// K = 512 (two 256-halves). Bt [N][512] n-major. Block = 128 thr (2 waves),
// tile BM=32*GRPS x 128, BK=32.
// VARIANT 0 (GRPS=2): A2 = fp32 x (converted in staging), out bf16 h + BN.
// VARIANT 1 (GRPS=1): A2 = bf16 h, out fp32 + bias.
template <int VARIANT, int GRPS>
__global__ __launch_bounds__(128) void gemm_mfma(
    const ushort* __restrict__ Alo,
    const ushort* __restrict__ A2b, const float* __restrict__ A2f,
    const ushort* __restrict__ Bt,
    const float* __restrict__ bias,
    const float* __restrict__ g, const float* __restrict__ bt,
    const float* __restrict__ rm, const float* __restrict__ rv,
    void* __restrict__ Cout, int M) {
    constexpr int BM = 32 * GRPS;         // 64 or 32
    constexpr int TPR = 128 / BM;         // threads per row: 2 or 4
    constexpr int CHUNK = 32 / TPR;       // bf16 per thread: 16 or 8
    __shared__ ushort As[BM][40];         // +8 pad
    __shared__ ushort Bs[128][40];
    int tid = threadIdx.x;
    int wave = tid >> 6, lane = tid & 63;
    int quad = lane >> 4, l16 = lane & 15;
    int m0 = blockIdx.y * BM, n0 = blockIdx.x * 128;
    f32x4 acc[GRPS][8] = {};
    int ar = tid / TPR;
    int ak = (tid % TPR) * CHUNK;
    int bn = tid;
    for (int k0 = 0; k0 < 512; k0 += 32) {
        uint4 a0 = make_uint4(0, 0, 0, 0), a1 = make_uint4(0, 0, 0, 0);
        bool inb = (m0 + ar) < M;
        if (k0 < 256) {
            if (inb) {
                const ushort* Ag = Alo + (size_t)(m0 + ar) * Dc + k0 + ak;
                a0 = *(const uint4*)Ag;
                if (CHUNK == 16) a1 = *(const uint4*)(Ag + 8);
            }
        } else if (VARIANT == 0) {        // fp32 x -> bf16 in-register
            if (inb) {
                const float* Af = A2f + (size_t)(m0 + ar) * Dc + (k0 - 256) + ak;
                float4 f0 = *(const float4*)(Af + 0);
                float4 f1 = *(const float4*)(Af + 4);
                a0 = make_uint4(pack2(f0.x, f0.y), pack2(f0.z, f0.w),
                                pack2(f1.x, f1.y), pack2(f1.z, f1.w));
                if (CHUNK == 16) {
                    float4 f2 = *(const float4*)(Af + 8);
                    float4 f3 = *(const float4*)(Af + 12);
                    a1 = make_uint4(pack2(f2.x, f2.y), pack2(f2.z, f2.w),
                                    pack2(f3.x, f3.y), pack2(f3.z, f3.w));
                }
            }
        } else {
            if (inb) {
                const ushort* Ag = A2b + (size_t)(m0 + ar) * Dc + (k0 - 256) + ak;
                a0 = *(const uint4*)Ag;
                if (CHUNK == 16) a1 = *(const uint4*)(Ag + 8);
            }
        }
        const ushort* Bg = Bt + (size_t)(n0 + bn) * 512 + k0;
        uint4 b0 = *(const uint4*)(Bg + 0);
        uint4 b1 = *(const uint4*)(Bg + 8);
        uint4 b2 = *(const uint4*)(Bg + 16);
        uint4 b3 = *(const uint4*)(Bg + 24);
        __syncthreads();                  // prior iter's LDS reads done
        *(uint4*)&As[ar][ak] = a0;
        if (CHUNK == 16) *(uint4*)&As[ar][ak + 8] = a1;
        *(uint4*)&Bs[bn][0] = b0;
        *(uint4*)&Bs[bn][8] = b1;
        *(uint4*)&Bs[bn][16] = b2;
        *(uint4*)&Bs[bn][24] = b3;
        __syncthreads();
        short8 af[GRPS];
#pragma unroll
        for (int grp = 0; grp < GRPS; ++grp)
            af[grp] = *(const short8*)&As[wave * 16 * GRPS + grp * 16 + l16][quad * 8];
#pragma unroll
        for (int j = 0; j < 8; ++j) {
            short8 bf = *(const short8*)&Bs[j * 16 + l16][quad * 8];
#pragma unroll
            for (int grp = 0; grp < GRPS; ++grp)
                acc[grp][j] = __builtin_amdgcn_mfma_f32_16x16x32_bf16(af[grp], bf, acc[grp][j], 0, 0, 0);
        }
    }
    // epilogue: C/D layout col=lane&15, row=quad*4+reg
#pragma unroll
    for (int grp = 0; grp < GRPS; ++grp) {
#pragma unroll
        for (int j = 0; j < 8; ++j) {
            int gn = n0 + j * 16 + l16;
            float sc = 1.f, sh = bias[gn];
            if (VARIANT == 0) {
                float s = g[gn] * rsqrtf(rv[gn] + EPSc);
                sh = (bias[gn] - rm[gn]) * s + bt[gn];
                sc = s;
            }
            int gmb = m0 + wave * 16 * GRPS + grp * 16 + quad * 4;
#pragma unroll
            for (int r = 0; r < 4; ++r) {
                int gm = gmb + r;
                if (gm >= M) continue;
                float v = acc[grp][j][r];
                if (VARIANT == 0) {
                    v = v * sc + sh;
                    v = v >= 0.f ? v : NEGc * v;
                    ((ushort*)Cout)[(size_t)gm * Dc + gn] = f2bf(v);
                } else {
                    ((float*)Cout)[(size_t)gm * DOUTc + gn] = v + sh;
                }
            }
        }
    }
}

extern "C" void kernel_launch(void* const* d_in, const int* in_sizes, int n_in,
                              void* d_out, int out_size, void* d_ws, size_t ws_size,
                              hipStream_t stream) {
    const float* x    = (const float*)d_in[0];
    const int* src0   = (const int*)d_in[1];
    const int* dst0   = (const int*)d_in[2];
    const int* val0   = (const int*)d_in[3];
    const int* src1   = (const int*)d_in[4];
    const int* dst1   = (const int*)d_in[5];
    const int* val1   = (const int*)d_in[6];
    const int* ts     = (const int*)d_in[7];
    const int* time_p = (const int*)d_in[8];
    const int* itv_p  = (const int*)d_in[9];
    const float* W1l  = (const float*)d_in[10];
    const float* W1r  = (const float*)d_in[11];
    const float* b1   = (const float*)d_in[12];
    const float* g1   = (const float*)d_in[13];
    const float* bt1  = (const float*)d_in[14];
    const float* rm1  = (const float*)d_in[15];
    const float* rv1  = (const float*)d_in[16];
    const float* W2l  = (const float*)d_in[17];
    const float* W2r  = (const float*)d_in[18];
    const float* b2   = (const float*)d_in[19];
    int E0 = in_sizes[1];
    int E1 = in_sizes[4];
    float* out = (float*)d_out;

    // ---- workspace layout ----
    ushort* agg0 = (ushort*)d_ws;                  // [N1][256]
    ushort* h    = agg0 + (size_t)N1c * Dc;        // [N1][256]
    ushort* agg1 = h    + (size_t)N1c * Dc;        // [N2][256]
    ushort* Bt1  = agg1 + (size_t)N2c * Dc;        // [256][512]
    ushort* Bt2  = Bt1  + 256 * 512;               // [128][512]
    int* ip      = (int*)(Bt2 + 128 * 512);
    int* count0   = ip;            ip += N1c;      // -- zeroed (memset)
    int* count1   = ip;            ip += N2c;      // -- zeroed (memset)
    int* offsets0 = ip;            ip += N1c;
    int* offsets1 = ip;            ip += N2c;
    int* eidx0    = ip;            ip += E0;
    int* eidx1    = ip;            ip += E1;
    float* mask_tail = out + (size_t)N2c * DOUTc;

    hipMemsetAsync(count0, 0, (size_t)(N1c + N2c) * sizeof(int), stream);

    prep_all<<<1024, 256, 0, stream>>>(
        dst0, val0, dst1, val1, ts, time_p, itv_p,
        W1l, W1r, W2l, W2r, E0, E1, Bt1, Bt2, count0, count1);
    scan_both<<<2, 1024, 0, stream>>>(count0, offsets0, count1, offsets1);
    fill_both<<<(E0 + E1 + 255) / 256, 256, 0, stream>>>(
        src0, dst0, val0, src1, dst1, val1, ts, time_p, itv_p,
        E0, E1, offsets0, offsets1, eidx0, eidx1, mask_tail);
    gather_f32<<<(N1c + 3) / 4, 256, 0, stream>>>(x, offsets0, eidx0, agg0, N1c);
    gemm_mfma<0, 2><<<dim3(2, (N1c + 63) / 64), 128, 0, stream>>>(
        agg0, nullptr, x, Bt1, b1, g1, bt1, rm1, rv1, h, N1c);
    gather_bf16<<<(N2c + 3) / 4, 256, 0, stream>>>(h, offsets1, eidx1, agg1, N2c);
    gemm_mfma<1, 1><<<dim3(1, (N2c + 31) / 32), 128, 0, stream>>>(
        agg1, h, nullptr, Bt2, b2, nullptr, nullptr, nullptr, nullptr, out, N2c);
}